// Round 5
// baseline (474.939 us; speedup 1.0000x reference)
//
#include <hip/hip_runtime.h>
#include <math.h>

// GCN 2-layer, f32 in/out. N=100000, E=3200000, F_in=512, H=16, C=7.
// Round 11: overlap the independent phases.
//   - hs1b now stores UNSCALED bf16(x@W1); dinv[src] is gathered + shuffle-
//     broadcast per edge in agg1 (breaks the k_b -> gemm1 dependency)
//   - gemm1's 1563 blocks are distributed across the 5 partition launches
//     (f1=a1, f2=a2a, f3=a2b, f4=a3, f5=k_b) via block-range specialization
//     with a shared-memory union; partition chain and gemm1 now co-run
//   - f3 zeroes csr[E..E+16) so agg1's unconditional dinv[evn] prefetch is safe
//   - agg1/agg2 gather structure unchanged from round 10 otherwise

#define F_IN 512
#define HID  16
#define NCLS 7
#define NCHUNK 256
#define BK 256        // nodes per bucket
#define NBMAX 400     // >= nb = ceil(N/256) = 391
#define CAP 9216      // LDS edge capacity in k_b (mean 8192, +11 sigma)
#define WT_STRIDE 516 // padded k-stride of transposed W1 in LDS
#define SM_GEMM (HID * WT_STRIDE * 4)        // 33024 B
#define SM_KB   (CAP * 4 + 3 * BK * 4)       // 39936 B

static __device__ __forceinline__ unsigned short f2bf(float f) {
    union { float f; unsigned int u; } v; v.f = f;
    unsigned int b = v.u;
    return (unsigned short)((b + 0x7FFFu + ((b >> 16) & 1u)) >> 16);  // RNE
}

// ================= device bodies =================

// GEMM1 body: hs1b[i][:] = bf16( x[i,:] @ W1 )  (UNSCALED)
// 16 lanes/row, 4 rows per lane-group; x loads pipelined 1-deep.
static __device__ void gemm_body(int gb, const float* __restrict__ x,
                                 const float* __restrict__ W1,
                                 unsigned short* __restrict__ hs1b, int N,
                                 float* wlT) {
    int lane = threadIdx.x & 15;
    int g = threadIdx.x >> 4;                 // lane-group 0..15
    int rbase = gb * 64 + g * 4;              // 4 rows per group

    const float* xp0 = x + (size_t)(rbase + 0 < N ? rbase + 0 : 0) * F_IN + 4 * lane;
    const float* xp1 = x + (size_t)(rbase + 1 < N ? rbase + 1 : 0) * F_IN + 4 * lane;
    const float* xp2 = x + (size_t)(rbase + 2 < N ? rbase + 2 : 0) * F_IN + 4 * lane;
    const float* xp3 = x + (size_t)(rbase + 3 < N ? rbase + 3 : 0) * F_IN + 4 * lane;

    // issue first x loads BEFORE staging: latency hidden under W1 stage
    float4 a0 = *(const float4*)(xp0);
    float4 a1 = *(const float4*)(xp1);
    float4 a2 = *(const float4*)(xp2);
    float4 a3 = *(const float4*)(xp3);

    {
        int j = threadIdx.x & 15;
        int k0 = threadIdx.x >> 4;
        for (int it = 0; it < F_IN / 16; ++it) {
            int k = k0 + 16 * it;
            wlT[j * WT_STRIDE + k] = W1[k * HID + j];
        }
    }
    __syncthreads();

    float acc[4][16];
#pragma unroll
    for (int r = 0; r < 4; ++r)
#pragma unroll
        for (int j = 0; j < 16; ++j) acc[r][j] = 0.0f;

    auto fma_block = [&](int p, const float4& A0, const float4& A1,
                         const float4& A2, const float4& A3) {
        const float* wb = &wlT[64 * p + 4 * lane];
#pragma unroll
        for (int j = 0; j < 16; ++j) {
            float4 w4 = *(const float4*)(wb + (size_t)j * WT_STRIDE);
            acc[0][j] = fmaf(A0.x, w4.x, fmaf(A0.y, w4.y, fmaf(A0.z, w4.z, fmaf(A0.w, w4.w, acc[0][j]))));
            acc[1][j] = fmaf(A1.x, w4.x, fmaf(A1.y, w4.y, fmaf(A1.z, w4.z, fmaf(A1.w, w4.w, acc[1][j]))));
            acc[2][j] = fmaf(A2.x, w4.x, fmaf(A2.y, w4.y, fmaf(A2.z, w4.z, fmaf(A2.w, w4.w, acc[2][j]))));
            acc[3][j] = fmaf(A3.x, w4.x, fmaf(A3.y, w4.y, fmaf(A3.z, w4.z, fmaf(A3.w, w4.w, acc[3][j]))));
        }
    };

#pragma unroll 1
    for (int p = 0; p < 7; ++p) {
        float4 n0 = *(const float4*)(xp0 + 64 * (p + 1));
        float4 n1 = *(const float4*)(xp1 + 64 * (p + 1));
        float4 n2 = *(const float4*)(xp2 + 64 * (p + 1));
        float4 n3 = *(const float4*)(xp3 + 64 * (p + 1));
        fma_block(p, a0, a1, a2, a3);
        a0 = n0; a1 = n1; a2 = n2; a3 = n3;
    }
    fma_block(7, a0, a1, a2, a3);

    // reduce-and-transpose across the 16 lanes: lane l ends with feature j=l.
    bool b8 = (lane & 8) != 0, b4 = (lane & 4) != 0, b2 = (lane & 2) != 0, b1 = (lane & 1) != 0;
#pragma unroll
    for (int r = 0; r < 4; ++r) {
#pragma unroll
        for (int j = 0; j < 8; ++j) {
            float lo = acc[r][j], hi = acc[r][j + 8];
            float keep = b8 ? hi : lo;
            float send = b8 ? lo : hi;
            acc[r][j] = keep + __shfl_xor(send, 8, 16);
        }
#pragma unroll
        for (int j = 0; j < 4; ++j) {
            float lo = acc[r][j], hi = acc[r][j + 4];
            float keep = b4 ? hi : lo;
            float send = b4 ? lo : hi;
            acc[r][j] = keep + __shfl_xor(send, 4, 16);
        }
#pragma unroll
        for (int j = 0; j < 2; ++j) {
            float lo = acc[r][j], hi = acc[r][j + 2];
            float keep = b2 ? hi : lo;
            float send = b2 ? lo : hi;
            acc[r][j] = keep + __shfl_xor(send, 2, 16);
        }
        {
            float lo = acc[r][0], hi = acc[r][1];
            float keep = b1 ? hi : lo;
            float send = b1 ? lo : hi;
            acc[r][0] = keep + __shfl_xor(send, 1, 16);
        }
        int row = rbase + r;
        if (row < N)
            hs1b[(size_t)row * HID + lane] = f2bf(acc[r][0]);
    }
}

// A1 body: per-chunk histogram over buckets (dst>>8)
static __device__ void a1_body(int c, const int* __restrict__ ei, int E, int perChunk,
                               int nb, int* __restrict__ bh, int* hist) {
    for (int t = threadIdx.x; t < nb; t += 256) hist[t] = 0;
    __syncthreads();
    const int* dst = ei + E;
    int s0 = c * perChunk;
    int s1 = min(s0 + perChunk, E);
    for (int e = s0 + threadIdx.x; e < s1; e += 256)
        atomicAdd(&hist[dst[e] >> 8], 1);
    __syncthreads();
    for (int t = threadIdx.x; t < nb; t += 256) bh[(size_t)c * nb + t] = hist[t];
}

// A2a body: per-bucket exclusive scan across the 256 chunks (in place) + total
static __device__ void a2a_body(int b, int* __restrict__ bh, int nb,
                                int* __restrict__ Tb, int* sd) {
    int tid = threadIdx.x;
    int v = bh[(size_t)tid * nb + b];
    sd[tid] = v;
    __syncthreads();
    for (int off = 1; off < 256; off <<= 1) {
        int t = (tid >= off) ? sd[tid - off] : 0;
        __syncthreads();
        sd[tid] += t;
        __syncthreads();
    }
    bh[(size_t)tid * nb + b] = sd[tid] - v;
    if (tid == 255) Tb[b] = sd[255];
}

// A2b body: exclusive scan of bucket totals -> bucket bases; zero csr pad
static __device__ void a2b_body(const int* __restrict__ Tb, int nb,
                                int* __restrict__ Bb, int* sd,
                                int* __restrict__ csr, int E) {
    int tid = threadIdx.x;
    if (tid < 16) csr[E + tid] = 0;  // pad for agg over-read prefetch
    int carry = 0;
    for (int base = 0; base < nb; base += 256) {
        int v = (base + tid < nb) ? Tb[base + tid] : 0;
        sd[tid] = v;
        __syncthreads();
        for (int off = 1; off < 256; off <<= 1) {
            int t = (tid >= off) ? sd[tid - off] : 0;
            __syncthreads();
            sd[tid] += t;
            __syncthreads();
        }
        if (base + tid < nb) Bb[base + tid] = carry + sd[tid] - v;
        carry += sd[255];
        __syncthreads();
    }
}

// A3 body: deterministic partition scatter, packed (dl<<20)|src
static __device__ void a3_body(int c, const int* __restrict__ ei, int E, int perChunk,
                               int nb, const int* __restrict__ bh,
                               const int* __restrict__ Bb,
                               unsigned* __restrict__ part,
                               int* cur, int* baseL) {
    for (int t = threadIdx.x; t < nb; t += 256) {
        cur[t] = 0;
        baseL[t] = Bb[t] + bh[(size_t)c * nb + t];
    }
    __syncthreads();
    const int* src = ei;
    const int* dst = ei + E;
    int s0 = c * perChunk;
    int s1 = min(s0 + perChunk, E);
    for (int e = s0 + threadIdx.x; e < s1; e += 256) {
        int s = src[e], d = dst[e];
        int b = d >> 8;
        int r = atomicAdd(&cur[b], 1);
        part[baseL[b] + r] = ((unsigned)(d & (BK - 1)) << 20) | (unsigned)s;
    }
}

// B body: per-bucket counting sort -> csr (sorted by dst), cnt, offs, dinv
static __device__ void kb_body(int b, const unsigned* __restrict__ part,
                               const int* __restrict__ Tb,
                               const int* __restrict__ Bb,
                               int* __restrict__ csr, int* __restrict__ cnt,
                               int* __restrict__ offs, float* __restrict__ dinv,
                               int N, unsigned* eL, int* hist, int* sd, int* cur) {
    int tid = threadIdx.x;
    int base = Bb[b], ct = Tb[b];
    hist[tid] = 0;
    __syncthreads();
    for (int k = tid; k < ct; k += 256) {
        unsigned v = part[base + k];
        if (k < CAP) eL[k] = v;
        atomicAdd(&hist[v >> 20], 1);
    }
    __syncthreads();
    sd[tid] = hist[tid];
    __syncthreads();
    for (int off = 1; off < BK; off <<= 1) {
        int t = (tid >= off) ? sd[tid - off] : 0;
        __syncthreads();
        sd[tid] += t;
        __syncthreads();
    }
    {
        int h = hist[tid];
        int ex = sd[tid] - h;
        cur[tid] = ex;
        int node = b * BK + tid;
        if (node < N) {
            cnt[node] = h;
            offs[node] = base + ex;
            dinv[node] = rsqrtf((float)h + 1.0f);
        }
    }
    __syncthreads();
    for (int k = tid; k < ct; k += 256) {
        unsigned v = (k < CAP) ? eL[k] : part[base + k];
        int dl = (int)(v >> 20);
        int r = atomicAdd(&cur[dl], 1);
        csr[base + r] = (int)(v & 0xFFFFFu);
    }
}

// ================= fused kernels =================

__global__ __launch_bounds__(256) void k_f1(const int* __restrict__ ei, int E, int perChunk,
                                            int nb, int* __restrict__ bh,
                                            const float* __restrict__ x,
                                            const float* __restrict__ W1,
                                            unsigned short* __restrict__ hs1b, int N,
                                            int gBase) {
    __shared__ __align__(16) unsigned char sm[SM_GEMM];
    if ((int)blockIdx.x < NCHUNK)
        a1_body(blockIdx.x, ei, E, perChunk, nb, bh, (int*)sm);
    else
        gemm_body(gBase + (int)blockIdx.x - NCHUNK, x, W1, hs1b, N, (float*)sm);
}

__global__ __launch_bounds__(256) void k_f2(int* __restrict__ bh, int nb,
                                            int* __restrict__ Tb,
                                            const float* __restrict__ x,
                                            const float* __restrict__ W1,
                                            unsigned short* __restrict__ hs1b, int N,
                                            int gBase) {
    __shared__ __align__(16) unsigned char sm[SM_GEMM];
    if ((int)blockIdx.x < nb)
        a2a_body(blockIdx.x, bh, nb, Tb, (int*)sm);
    else
        gemm_body(gBase + (int)blockIdx.x - nb, x, W1, hs1b, N, (float*)sm);
}

__global__ __launch_bounds__(256) void k_f3(const int* __restrict__ Tb, int nb,
                                            int* __restrict__ Bb,
                                            int* __restrict__ csr, int E,
                                            const float* __restrict__ x,
                                            const float* __restrict__ W1,
                                            unsigned short* __restrict__ hs1b, int N,
                                            int gBase) {
    __shared__ __align__(16) unsigned char sm[SM_GEMM];
    if ((int)blockIdx.x < 1)
        a2b_body(Tb, nb, Bb, (int*)sm, csr, E);
    else
        gemm_body(gBase + (int)blockIdx.x - 1, x, W1, hs1b, N, (float*)sm);
}

__global__ __launch_bounds__(256) void k_f4(const int* __restrict__ ei, int E, int perChunk,
                                            int nb, const int* __restrict__ bh,
                                            const int* __restrict__ Bb,
                                            unsigned* __restrict__ part,
                                            const float* __restrict__ x,
                                            const float* __restrict__ W1,
                                            unsigned short* __restrict__ hs1b, int N,
                                            int gBase) {
    __shared__ __align__(16) unsigned char sm[SM_GEMM];
    if ((int)blockIdx.x < NCHUNK)
        a3_body(blockIdx.x, ei, E, perChunk, nb, bh, Bb, part,
                (int*)sm, (int*)(sm + 4 * NBMAX));
    else
        gemm_body(gBase + (int)blockIdx.x - NCHUNK, x, W1, hs1b, N, (float*)sm);
}

__global__ __launch_bounds__(256) void k_f5(const unsigned* __restrict__ part,
                                            const int* __restrict__ Tb,
                                            const int* __restrict__ Bb,
                                            int* __restrict__ csr, int* __restrict__ cnt,
                                            int* __restrict__ offs, float* __restrict__ dinv,
                                            int nb,
                                            const float* __restrict__ x,
                                            const float* __restrict__ W1,
                                            unsigned short* __restrict__ hs1b, int N,
                                            int gBase) {
    __shared__ __align__(16) unsigned char sm[SM_KB];
    if ((int)blockIdx.x < nb)
        kb_body(blockIdx.x, part, Tb, Bb, csr, cnt, offs, dinv, N,
                (unsigned*)sm, (int*)(sm + 4 * CAP),
                (int*)(sm + 4 * CAP + 4 * BK), (int*)(sm + 4 * CAP + 8 * BK));
    else
        gemm_body(gBase + (int)blockIdx.x - nb, x, W1, hs1b, N, (float*)sm);
}

// ---- AGG1: CSR gather (+ per-edge dinv[src]) + b1 + relu + @W2 + *dinv -> hs2p ----
// 8 lanes/node, lane owns features (2l,2l+1) as one u32 (bf16 pair).
// csr+dinv batches prefetched 1-deep (padded over-read; pad zeroed in f3).
__global__ __launch_bounds__(256) void k_agg1(const int* __restrict__ csr,
                                              const int* __restrict__ offs,
                                              const int* __restrict__ cnt,
                                              const float* __restrict__ dinv,
                                              const unsigned* __restrict__ hs1u,
                                              const float* __restrict__ b1,
                                              const float* __restrict__ W2,
                                              float* __restrict__ hs2p, int N) {
    int lane = threadIdx.x & 7;
    int i = blockIdx.x * 32 + (threadIdx.x >> 3);
    float w2a[NCLS], w2b[NCLS];
#pragma unroll
    for (int c = 0; c < NCLS; c++) {
        w2a[c] = W2[(2 * lane) * NCLS + c];
        w2b[c] = W2[(2 * lane + 1) * NCLS + c];
    }
    float b1a = b1[2 * lane], b1b = b1[2 * lane + 1];
    if (i >= N) return;  // group-uniform
    int start = offs[i], cn = cnt[i];
    float dvi = dinv[i];
    unsigned su = hs1u[(size_t)i * 8 + lane];  // self-loop (unscaled)
    float accA = dvi * __uint_as_float(su << 16);
    float accB = dvi * __uint_as_float(su & 0xffff0000u);
    int full = cn & ~7;
    int rem = cn - full;
    int evn = csr[start + lane];               // padded: safe over-read
    float dvn = dinv[evn];                     // evn always a valid node or 0
    for (int k = 0; k < full; k += 8) {
        int ev = evn; float dvv = dvn;
        evn = csr[start + k + 8 + lane];       // prefetch next batch
        dvn = dinv[evn];
#pragma unroll
        for (int t = 0; t < 8; ++t) {
            int s = __shfl(ev, t, 8);
            float ds = __shfl(dvv, t, 8);
            unsigned u = hs1u[(size_t)s * 8 + lane];
            accA = fmaf(ds, __uint_as_float(u << 16), accA);
            accB = fmaf(ds, __uint_as_float(u & 0xffff0000u), accB);
        }
    }
    for (int t = 0; t < rem; ++t) {
        int s = __shfl(evn, t, 8);
        float ds = __shfl(dvn, t, 8);
        unsigned u = hs1u[(size_t)s * 8 + lane];
        accA = fmaf(ds, __uint_as_float(u << 16), accA);
        accB = fmaf(ds, __uint_as_float(u & 0xffff0000u), accB);
    }
    float vA = fmaf(dvi, accA, b1a);
    float vB = fmaf(dvi, accB, b1b);
    float hA = vA > 0.0f ? vA : 0.0f;
    float hB = vB > 0.0f ? vB : 0.0f;
    float res[NCLS];
#pragma unroll
    for (int c = 0; c < NCLS; c++) {
        float t = fmaf(hA, w2a[c], hB * w2b[c]);
#pragma unroll
        for (int w = 4; w >= 1; w >>= 1) t += __shfl_xor(t, w, 8);
        res[c] = t;
    }
    float o = res[0];
#pragma unroll
    for (int c = 1; c < NCLS; c++) o = (lane == c) ? res[c] : o;
    hs2p[(size_t)i * 8 + lane] = dvi * o;  // lane 7 writes dvi*res[0] (pad, unused)
}

// ---- AGG2: CSR gather (8 f32/row padded) + b2 + log_softmax -> out ----
// 8 lanes/node; csr batches prefetched 1-deep; aligned 32B rows.
__global__ __launch_bounds__(256) void k_agg2(const int* __restrict__ csr,
                                              const int* __restrict__ offs,
                                              const int* __restrict__ cnt,
                                              const float* __restrict__ dinv,
                                              const float* __restrict__ hs2p,
                                              const float* __restrict__ b2,
                                              float* __restrict__ out, int N) {
    int lane = threadIdx.x & 7;
    int i = blockIdx.x * 32 + (threadIdx.x >> 3);
    if (i >= N) return;  // group-uniform
    int start = offs[i], cn = cnt[i];
    float acc = hs2p[(size_t)i * 8 + lane];  // self-loop (pre-scaled)
    int full = cn & ~7;
    int rem = cn - full;
    int evn = csr[start + lane];             // padded: safe over-read
    for (int k = 0; k < full; k += 8) {
        int ev = evn;
        evn = csr[start + k + 8 + lane];     // prefetch next batch
#pragma unroll
        for (int t = 0; t < 8; ++t) {
            int s = __shfl(ev, t, 8);
            acc += hs2p[(size_t)s * 8 + lane];
        }
    }
    for (int t = 0; t < rem; ++t) {
        int s = __shfl(evn, t, 8);
        acc += hs2p[(size_t)s * 8 + lane];
    }
    int cc = lane < NCLS ? lane : NCLS - 1;
    float v = fmaf(dinv[i], acc, b2[cc]);
    float vm = (lane < NCLS) ? v : -INFINITY;
    float m = vm;
#pragma unroll
    for (int w = 4; w >= 1; w >>= 1) m = fmaxf(m, __shfl_xor(m, w, 8));
    float e = (lane < NCLS) ? expf(v - m) : 0.0f;
    float ssum = e;
#pragma unroll
    for (int w = 4; w >= 1; w >>= 1) ssum += __shfl_xor(ssum, w, 8);
    if (lane < NCLS) out[(size_t)i * NCLS + lane] = v - m - logf(ssum);
}

extern "C" void kernel_launch(void* const* d_in, const int* in_sizes, int n_in,
                              void* d_out, int out_size, void* d_ws, size_t ws_size,
                              hipStream_t stream) {
    const float* x  = (const float*)d_in[0];
    const int*   ei = (const int*)d_in[1];
    const float* W1 = (const float*)d_in[2];
    const float* b1 = (const float*)d_in[3];
    const float* W2 = (const float*)d_in[4];
    const float* b2 = (const float*)d_in[5];
    float* out = (float*)d_out;

    const int N = in_sizes[0] / F_IN;          // 100000
    const int E = in_sizes[1] / 2;             // 3200000
    const int nb = (N + BK - 1) / BK;          // 391
    const int perChunk = (E + NCHUNK - 1) / NCHUNK;  // 12500

    // gemm block distribution across the 5 partition launches
    const int gemmNB = (N + 63) / 64;          // 1563
    const int g1 = gemmNB * 13 / 100;
    const int g2 = gemmNB * 12 / 100;
    const int g3 = gemmNB * 3 / 100;
    const int g4 = gemmNB * 32 / 100;
    const int g5 = gemmNB - g1 - g2 - g3 - g4;
    const int gb1 = 0, gb2 = g1, gb3 = g1 + g2, gb4 = g1 + g2 + g3,
              gb5 = g1 + g2 + g3 + g4;

    // ws layout in 4B words, 16B-aligned chunks:
    // [part E | hs2p 8N (aliased; part dead after k_f5)][csr E+16][hs1b 8N(u32)]
    // [dinv N][cnt N][offs N][bh 256*nb][Tb nb][Bb nb]
    unsigned* w = (unsigned*)d_ws;
    auto al4 = [](size_t v) { return (v + 3) & ~(size_t)3; };
    size_t o = 0;
    unsigned*       part = w + o;
    float*          hs2p = (float*)(w + o);     o = al4(o + E);
    int*            csr  = (int*)(w + o);       o = al4(o + E + 16);
    unsigned short* hs1b = (unsigned short*)(w + o); o = al4(o + (size_t)N * HID / 2);
    float*          dinv = (float*)(w + o);     o = al4(o + N);
    int*            cnt  = (int*)(w + o);       o = al4(o + N);
    int*            offs = (int*)(w + o);       o = al4(o + N);
    int*            bh   = (int*)(w + o);       o = al4(o + (size_t)NCHUNK * nb);
    int*            Tb   = (int*)(w + o);       o = al4(o + nb);
    int*            Bb   = (int*)(w + o);

    k_f1<<<NCHUNK + g1, 256, 0, stream>>>(ei, E, perChunk, nb, bh, x, W1, hs1b, N, gb1);
    k_f2<<<nb + g2, 256, 0, stream>>>(bh, nb, Tb, x, W1, hs1b, N, gb2);
    k_f3<<<1 + g3, 256, 0, stream>>>(Tb, nb, Bb, csr, E, x, W1, hs1b, N, gb3);
    k_f4<<<NCHUNK + g4, 256, 0, stream>>>(ei, E, perChunk, nb, bh, Bb, part, x, W1, hs1b, N, gb4);
    k_f5<<<nb + g5, 256, 0, stream>>>(part, Tb, Bb, csr, cnt, offs, dinv, nb, x, W1, hs1b, N, gb5);
    k_agg1<<<(N + 31) / 32, 256, 0, stream>>>(csr, offs, cnt, dinv,
                                              (const unsigned*)hs1b, b1, W2, hs2p, N);
    k_agg2<<<(N + 31) / 32, 256, 0, stream>>>(csr, offs, cnt, dinv, hs2p, b2, out, N);
}